// Round 10
// baseline (264.259 us; speedup 1.0000x reference)
//
#include <hip/hip_runtime.h>
#include <hip/hip_bf16.h>
#include <stdint.h>

// CrossAttention: out = softmax((x@Wq)(ctx@Wk)^T * scale) @ (ctx@Wv) @ Wo + bo
// B=16, NQ=4096, NK=77, QD=512, CD=768, H=8, DH=64, INNER=512
//
// Round 10: UN-FUSE. The 16-wave qattn mega-block was LDS-pipe + lockstep
// bound (whole-CU drains at every barrier). Replace with:
//   qproj: m97-skeleton GEMM (4-wave blocks), f32-A reg-staged+cvt, -> Qb
//   attn3: standalone 512-thr blocks, 1 barrier, conflict-free strides
// O-proj (m97+swizzle), K/V prep unchanged. Vtg stride 96 -> 104.

typedef __attribute__((ext_vector_type(8))) short bf16x8;
typedef __attribute__((ext_vector_type(4))) float f32x4;
typedef __attribute__((ext_vector_type(4))) short short4v;
typedef __attribute__((ext_vector_type(4))) float float4v;
typedef __attribute__((ext_vector_type(2))) unsigned uint2v;
typedef __attribute__((ext_vector_type(4))) unsigned uint4v;

#define DEVINL __device__ __forceinline__

DEVINL short f2bf(float f) {
  unsigned u = __builtin_bit_cast(unsigned, f);
  unsigned r = (u + 0x7FFFu + ((u >> 16) & 1u)) >> 16;  // RNE
  return (short)(unsigned short)r;
}

// packed f32x2 -> bf16x2 (RTNE), single VALU op
DEVINL unsigned pkbf(float lo, float hi) {
  unsigned r;
  asm("v_cvt_pk_bf16_f32 %0, %1, %2" : "=v"(r) : "v"(lo), "v"(hi));
  return r;
}

#define GLDS16(gp, sp)                                                \
  __builtin_amdgcn_global_load_lds(                                   \
      (const __attribute__((address_space(1))) void*)(gp),            \
      (__attribute__((address_space(3))) void*)(sp), 16, 0, 0)

// ---------------- zero fill (float4 granules) ------------------------------
__global__ __launch_bounds__(256) void fill0(float4v* __restrict__ p, int n4) {
  int i = blockIdx.x * 256 + threadIdx.x;
  if (i < n4) p[i] = float4v{0.f, 0.f, 0.f, 0.f};
}

// ---------------- weight transpose+convert: W[K][N] f32 -> Wt[N][K] bf16 ----
__global__ __launch_bounds__(256) void wt_conv(const float* __restrict__ W,
                                               short* __restrict__ Wt,
                                               int K, int N) {
  __shared__ short Tl[64][65];
  const int kt = blockIdx.y * 64, nt = blockIdx.x * 64;
#pragma unroll
  for (int i = 0; i < 16; ++i) {
    int idx = threadIdx.x + i * 256;
    int r = idx >> 6, c = idx & 63;
    Tl[c][r] = f2bf(W[(size_t)(kt + r) * N + nt + c]);
  }
  __syncthreads();
#pragma unroll
  for (int i = 0; i < 16; ++i) {
    int idx = threadIdx.x + i * 256;
    int r = idx >> 6, c = idx & 63;
    Wt[(size_t)(nt + r) * K + kt + c] = Tl[r][c];
  }
}

// ---------------- m97-structure GEMM + XCD swizzle --------------------------
// C[M][N] = A[M][K] @ Bt[N][K]^T, bf16 in. 128x128 tile, BK=64, 4 waves.
// 1-D grid = (M/128)*(N/128), must be %8==0. OUT: 0=bf16, 2=f32+bias.
template <int OUT>
__global__ __launch_bounds__(256) void gemm_m97(const short* __restrict__ A,
                                                const short* __restrict__ Bt,
                                                void* __restrict__ Cv,
                                                const float* __restrict__ bias,
                                                int M, int N, int K) {
  __shared__ short Al[128 * 64];
  __shared__ short Bl[128 * 64];

  const int tid = threadIdx.x;
  const int lane = tid & 63, w = tid >> 6;
  const int wm = w >> 1, wn = w & 1;
  const int quad = lane >> 4, l16 = lane & 15;

  const int nwg = gridDim.x;
  const int cpx = nwg >> 3;
  const int wg = blockIdx.x;
  const int swz = (wg & 7) * cpx + (wg >> 3);
  const int nnt = N >> 7;
  const int m0 = (swz / nnt) * 128, n0 = (swz % nnt) * 128;

  const int lr = lane >> 3;
  const int lc = (lane & 7) * 8;

  f32x4 acc[4][4] = {};

  for (int k0 = 0; k0 < K; k0 += 64) {
#pragma unroll
    for (int p = 0; p < 4; ++p) {
      const int row = w * 32 + p * 8;
      GLDS16(A + (size_t)(m0 + row + lr) * K + k0 + lc, &Al[row * 64]);
      GLDS16(Bt + (size_t)(n0 + row + lr) * K + k0 + lc, &Bl[row * 64]);
    }
    __syncthreads();

#pragma unroll
    for (int ks = 0; ks < 2; ++ks) {
      bf16x8 af[4], bfr[4];
#pragma unroll
      for (int m = 0; m < 4; ++m)
        af[m] = *(bf16x8*)&Al[(wm * 64 + m * 16 + l16) * 64 + ks * 32 + quad * 8];
#pragma unroll
      for (int n = 0; n < 4; ++n)
        bfr[n] = *(bf16x8*)&Bl[(wn * 64 + n * 16 + l16) * 64 + ks * 32 + quad * 8];
#pragma unroll
      for (int m = 0; m < 4; ++m)
#pragma unroll
        for (int n = 0; n < 4; ++n)
          acc[m][n] = __builtin_amdgcn_mfma_f32_16x16x32_bf16(af[m], bfr[n],
                                                              acc[m][n], 0, 0, 0);
    }
    __syncthreads();
  }

#pragma unroll
  for (int m = 0; m < 4; ++m) {
#pragma unroll
    for (int n = 0; n < 4; ++n) {
      const int col = n0 + wn * 64 + n * 16 + l16;
      const int rowb = m0 + wm * 64 + m * 16 + quad * 4;
      const float badd = (OUT == 2) ? bias[col] : 0.0f;
#pragma unroll
      for (int r = 0; r < 4; ++r) {
        if constexpr (OUT == 0)
          ((short*)Cv)[(size_t)(rowb + r) * N + col] = f2bf(acc[m][n][r]);
        else
          ((float*)Cv)[(size_t)(rowb + r) * N + col] = acc[m][n][r] + badd;
      }
    }
  }
}

// ---------------- Q projection: Qb = x(f32) @ wqt^T, m97 skeleton -----------
// A f32 reg-staged+cvt into padded As[128][72]; B via GLDS (linear).
// M=65536, N=512, K=512. Grid 2048 (XCD-swizzled), 256 thr.
__global__ __launch_bounds__(256) void qproj(const float* __restrict__ A,
                                             const short* __restrict__ Bt,
                                             short* __restrict__ C) {
  __shared__ short As[128 * 72];  // 18432 B, padded (quad-step 9 -> no confl)
  __shared__ short Bs[128 * 64];  // 16384 B, linear (GLDS)

  const int tid = threadIdx.x;
  const int lane = tid & 63, w = tid >> 6;
  const int wm = w >> 1, wn = w & 1;
  const int quad = lane >> 4, l16 = lane & 15;

  const int cpx = gridDim.x >> 3;
  const int swz = (blockIdx.x & 7) * cpx + (blockIdx.x >> 3);
  const int m0 = (swz >> 2) * 128, n0 = (swz & 3) * 128;  // N/128 = 4

  const int lr = lane >> 3, lc = (lane & 7) * 8;
  const int ar = tid >> 1, ah = (tid & 1) * 32;  // A-staging: row, col-half

  f32x4 acc[4][4] = {};

  for (int k0 = 0; k0 < 512; k0 += 64) {
    // B tile [128][64] via GLDS
#pragma unroll
    for (int p = 0; p < 4; ++p) {
      const int row = w * 32 + p * 8;
      GLDS16(Bt + (size_t)(n0 + row + lr) * 512 + k0 + lc, &Bs[row * 64]);
    }
    // A tile [128][64] f32 -> bf16, reg-staged (32 floats/thread)
    {
      const float* ap = A + (size_t)(m0 + ar) * 512 + k0 + ah;
      float4v v0 = *(const float4v*)(ap);
      float4v v1 = *(const float4v*)(ap + 4);
      float4v v2 = *(const float4v*)(ap + 8);
      float4v v3 = *(const float4v*)(ap + 12);
      float4v v4 = *(const float4v*)(ap + 16);
      float4v v5 = *(const float4v*)(ap + 20);
      float4v v6 = *(const float4v*)(ap + 24);
      float4v v7 = *(const float4v*)(ap + 28);
      uint4v u0 = {pkbf(v0[0], v0[1]), pkbf(v0[2], v0[3]),
                   pkbf(v1[0], v1[1]), pkbf(v1[2], v1[3])};
      uint4v u1 = {pkbf(v2[0], v2[1]), pkbf(v2[2], v2[3]),
                   pkbf(v3[0], v3[1]), pkbf(v3[2], v3[3])};
      uint4v u2 = {pkbf(v4[0], v4[1]), pkbf(v4[2], v4[3]),
                   pkbf(v5[0], v5[1]), pkbf(v5[2], v5[3])};
      uint4v u3 = {pkbf(v6[0], v6[1]), pkbf(v6[2], v6[3]),
                   pkbf(v7[0], v7[1]), pkbf(v7[2], v7[3])};
      short* dp = &As[ar * 72 + ah];
      *(uint4v*)(dp) = u0;
      *(uint4v*)(dp + 8) = u1;
      *(uint4v*)(dp + 16) = u2;
      *(uint4v*)(dp + 24) = u3;
    }
    __syncthreads();

#pragma unroll
    for (int ks = 0; ks < 2; ++ks) {
      bf16x8 af[4], bfr[4];
#pragma unroll
      for (int m = 0; m < 4; ++m)
        af[m] = *(bf16x8*)&As[(wm * 64 + m * 16 + l16) * 72 + ks * 32 + quad * 8];
#pragma unroll
      for (int n = 0; n < 4; ++n)
        bfr[n] = *(bf16x8*)&Bs[(wn * 64 + n * 16 + l16) * 64 + ks * 32 + quad * 8];
#pragma unroll
      for (int m = 0; m < 4; ++m)
#pragma unroll
        for (int n = 0; n < 4; ++n)
          acc[m][n] = __builtin_amdgcn_mfma_f32_16x16x32_bf16(af[m], bfr[n],
                                                              acc[m][n], 0, 0, 0);
    }
    __syncthreads();
  }

#pragma unroll
  for (int m = 0; m < 4; ++m)
#pragma unroll
    for (int n = 0; n < 4; ++n) {
      const int col = n0 + wn * 64 + n * 16 + l16;
      const int rowb = m0 + wm * 64 + m * 16 + quad * 4;
#pragma unroll
      for (int r = 0; r < 4; ++r)
        C[(size_t)(rowb + r) * 512 + col] = f2bf(acc[m][n][r]);
    }
}

// ---------------- small GEMM (f32 A): C = A[M][K]f32 @ Bt[512][K]^T ---------
// TRANS=0: bf16 C[M][512].  TRANS=1: scatter to Vtg[((b*8+h)*64+d)*104+key].
template <int TRANS>
__global__ __launch_bounds__(256) void gemm_small(const float* __restrict__ A,
                                                  const short* __restrict__ Bt,
                                                  short* __restrict__ C,
                                                  int M, int K) {
  __shared__ short Al[32][40];
  __shared__ short Bl[128][40];

  const int tid = threadIdx.x;
  const int lane = tid & 63, wid = tid >> 6;
  const int wm = wid >> 1, wn = wid & 1;
  const int quad = lane >> 4, l16 = lane & 15;
  const int m0 = blockIdx.y * 32, n0 = blockIdx.x * 128;

  f32x4 acc[4] = {};

  for (int k0 = 0; k0 < K; k0 += 32) {
    for (int idx = tid; idx < 32 * 8; idx += 256) {
      int row = idx >> 3, kq = idx & 7;
      float4v v = {};
      if (m0 + row < M)
        v = *(const float4v*)(A + (size_t)(m0 + row) * K + k0 + kq * 4);
      short4v s = {f2bf(v[0]), f2bf(v[1]), f2bf(v[2]), f2bf(v[3])};
      *(short4v*)&Al[row][kq * 4] = s;
    }
    for (int idx = tid; idx < 512; idx += 256) {
      int row = idx >> 2, kq = idx & 3;
      *(bf16x8*)&Bl[row][kq * 8] =
          *(const bf16x8*)(Bt + (size_t)(n0 + row) * K + k0 + kq * 8);
    }
    __syncthreads();

    bf16x8 a = *(bf16x8*)&Al[wm * 16 + l16][quad * 8];
#pragma unroll
    for (int n = 0; n < 4; ++n) {
      bf16x8 b = *(bf16x8*)&Bl[wn * 64 + n * 16 + l16][quad * 8];
      acc[n] = __builtin_amdgcn_mfma_f32_16x16x32_bf16(a, b, acc[n], 0, 0, 0);
    }
    __syncthreads();
  }

#pragma unroll
  for (int n = 0; n < 4; ++n) {
    const int col = n0 + wn * 64 + n * 16 + l16;
    const int rowb = m0 + wm * 16 + quad * 4;
#pragma unroll
    for (int r = 0; r < 4; ++r) {
      const int rr = rowb + r;
      if (rr < M) {
        if constexpr (TRANS == 0) {
          C[(size_t)rr * 512 + col] = f2bf(acc[n][r]);
        } else {
          const int bb = rr / 77, key = rr - bb * 77;
          C[(size_t)((bb * 8 + (col >> 6)) * 64 + (col & 63)) * 104 + key] =
              f2bf(acc[n][r]);
        }
      }
    }
  }
}

// ---------------- standalone attention -------------------------------------
// 512 thr (8 waves), block = (qtile of 128 rows, head, batch). Each wave owns
// 16 q-rows; Q from global; K [80][72] LDS; V^T [64][104] GLDS; P per-wave
// (no QK->PV barrier). Exactly ONE __syncthreads per block.
__global__ __launch_bounds__(512) void attn3(const short* __restrict__ Qb,
                                             const short* __restrict__ Kb,
                                             const short* __restrict__ Vtg,
                                             short* __restrict__ AOb) {
  __shared__ short Kl[80 * 72];       // 11520 B (rows 77..79 uninit, masked)
  __shared__ short Vt[64 * 104];      // 13312 B
  __shared__ short Pw[8 * 16 * 104];  // 26624 B

  const int tid = threadIdx.x;
  const int lane = tid & 63, w = tid >> 6;
  const int quad = lane >> 4, l16 = lane & 15;
  const int qt = blockIdx.x, h = blockIdx.y, b = blockIdx.z;
  const size_t kbase = ((size_t)b * 77) * 512 + h * 64;

  // stage K rows 0..76 (8 b128 per row)
  for (int idx = tid; idx < 616; idx += 512) {
    const int r = idx >> 3, c = (idx & 7) * 8;
    *(bf16x8*)&Kl[r * 72 + c] =
        *(const bf16x8*)(Kb + kbase + (size_t)r * 512 + c);
  }
  // stage V^T linearly via GLDS (13 chunks of 1 KB)
  for (int cid = w; cid < 13; cid += 8)
    GLDS16(Vtg + (size_t)(b * 8 + h) * 6656 + cid * 512 + lane * 8,
           &Vt[cid * 512]);
  __syncthreads();

  const size_t qrow = (size_t)b * 4096 + qt * 128 + w * 16 + l16;
  const short* qp = Qb + qrow * 512 + h * 64;

  // Q fragment (B operand of sim^T = K . Q^T): col=q=l16, k=d
  bf16x8 qfr[2];
#pragma unroll
  for (int ks = 0; ks < 2; ++ks)
    qfr[ks] = *(const bf16x8*)(qp + ks * 32 + quad * 8);

  // sim^T: 5 frags of 16 keys x 16 q
  f32x4 c[5] = {};
#pragma unroll
  for (int f = 0; f < 5; ++f)
#pragma unroll
    for (int ks = 0; ks < 2; ++ks) {
      bf16x8 a = *(bf16x8*)&Kl[(f * 16 + l16) * 72 + ks * 32 + quad * 8];
      c[f] = __builtin_amdgcn_mfma_f32_16x16x32_bf16(a, qfr[ks], c[f], 0, 0, 0);
    }

  // scale + mask + softmax over keys
  float mx = -1e30f;
#pragma unroll
  for (int f = 0; f < 5; ++f)
#pragma unroll
    for (int r = 0; r < 4; ++r) {
      const int key = f * 16 + quad * 4 + r;
      float v = c[f][r] * 0.125f;
      v = (key < 77) ? v : -1e30f;
      c[f][r] = v;
      mx = fmaxf(mx, v);
    }
  mx = fmaxf(mx, __shfl_xor(mx, 16));
  mx = fmaxf(mx, __shfl_xor(mx, 32));

  short* pbase = Pw + (w * 16 + l16) * 104;
  float sum = 0.f;
#pragma unroll
  for (int f = 0; f < 5; ++f) {
    float e0 = __expf(c[f][0] - mx), e1 = __expf(c[f][1] - mx);
    float e2 = __expf(c[f][2] - mx), e3 = __expf(c[f][3] - mx);
    sum += (e0 + e1) + (e2 + e3);
    uint2v sv2 = {pkbf(e0, e1), pkbf(e2, e3)};
    *(uint2v*)(pbase + f * 16 + quad * 4) = sv2;
  }
  sum += __shfl_xor(sum, 16);
  sum += __shfl_xor(sum, 32);
  const float inv = 1.0f / sum;

  // P fragments: keys 0..63 from LDS; keys 64..79 for quad<2; 80..95 zero.
  bf16x8 pb0 = *(bf16x8*)(pbase + quad * 8);
  bf16x8 pb1 = *(bf16x8*)(pbase + 32 + quad * 8);
  bf16x8 pb2 = bf16x8{0, 0, 0, 0, 0, 0, 0, 0};
  if (quad < 2) pb2 = *(bf16x8*)(pbase + 64 + quad * 8);

  // out^T = V^T . P^T
  f32x4 o[4] = {};
#pragma unroll
  for (int mt = 0; mt < 4; ++mt) {
    const short* vrow = &Vt[(mt * 16 + l16) * 104];
    o[mt] = __builtin_amdgcn_mfma_f32_16x16x32_bf16(
        *(bf16x8*)(vrow + quad * 8), pb0, o[mt], 0, 0, 0);
    o[mt] = __builtin_amdgcn_mfma_f32_16x16x32_bf16(
        *(bf16x8*)(vrow + 32 + quad * 8), pb1, o[mt], 0, 0, 0);
    o[mt] = __builtin_amdgcn_mfma_f32_16x16x32_bf16(
        *(bf16x8*)(vrow + 64 + quad * 8), pb2, o[mt], 0, 0, 0);
  }

  short* op = AOb + qrow * 512 + h * 64;
#pragma unroll
  for (int mt = 0; mt < 4; ++mt) {
    uint2v sv2 = {pkbf(o[mt][0] * inv, o[mt][1] * inv),
                  pkbf(o[mt][2] * inv, o[mt][3] * inv)};
    *(uint2v*)(op + mt * 16 + quad * 4) = sv2;
  }
}

extern "C" void kernel_launch(void* const* d_in, const int* in_sizes, int n_in,
                              void* d_out, int out_size, void* d_ws, size_t ws_size,
                              hipStream_t stream) {
  const float* x   = (const float*)d_in[0];
  const float* ctx = (const float*)d_in[1];
  const float* Wq  = (const float*)d_in[2];
  const float* Wk  = (const float*)d_in[3];
  const float* Wv  = (const float*)d_in[4];
  const float* Wo  = (const float*)d_in[5];
  const float* bo  = (const float*)d_in[6];
  float* out = (float*)d_out;

  char* ws = (char*)d_ws;
  size_t off = 0;
  short* wqt = (short*)(ws + off); off += 512 * 512 * 2;
  short* wkt = (short*)(ws + off); off += 768 * 512 * 2;
  short* wvt = (short*)(ws + off); off += 768 * 512 * 2;
  short* wot = (short*)(ws + off); off += 512 * 512 * 2;
  short* Kb  = (short*)(ws + off); off += 1232 * 512 * 2;
  short* Vtg = (short*)(ws + off); off += (size_t)16 * 8 * 64 * 104 * 2;
  short* Qb  = (short*)(ws + off); off += (size_t)65536 * 512 * 2;
  short* AOb = (short*)(ws + off); off += (size_t)65536 * 512 * 2;

  // weights -> bf16 transposed [N][K]
  wt_conv<<<dim3(8, 8), 256, 0, stream>>>(Wq, wqt, 512, 512);
  wt_conv<<<dim3(8, 12), 256, 0, stream>>>(Wk, wkt, 768, 512);
  wt_conv<<<dim3(8, 12), 256, 0, stream>>>(Wv, wvt, 768, 512);
  wt_conv<<<dim3(8, 8), 256, 0, stream>>>(Wo, wot, 512, 512);

  // zero-fill Vtg pads (16*8*64*104*2 B / 16 = 106496 float4)
  fill0<<<416, 256, 0, stream>>>((float4v*)Vtg, 106496);
  gemm_small<0><<<dim3(4, 39), 256, 0, stream>>>(ctx, wkt, Kb, 1232, 768);
  gemm_small<1><<<dim3(4, 39), 256, 0, stream>>>(ctx, wvt, Vtg, 1232, 768);

  // Q projection (f32 A) -> Qb bf16
  qproj<<<2048, 256, 0, stream>>>(x, wqt, Qb);

  // standalone attention -> AOb bf16
  attn3<<<dim3(32, 8, 16), 512, 0, stream>>>(Qb, Kb, Vtg, AOb);

  // output projection + bias -> f32 d_out
  gemm_m97<2><<<2048, 256, 0, stream>>>(AOb, wot, out, bo, 65536, 512, 512);
}

// Round 11
// 263.792 us; speedup vs baseline: 1.0018x; 1.0018x over previous
//
#include <hip/hip_runtime.h>
#include <hip/hip_bf16.h>
#include <stdint.h>

// CrossAttention: out = softmax((x@Wq)(ctx@Wk)^T * scale) @ (ctx@Wv) @ Wo + bo
// B=16, NQ=4096, NK=77, QD=512, CD=768, H=8, DH=64, INNER=512
//
// Round 11: 2-phase double-buffered GEMMs (T3-minimum recipe):
//   STAGE(next tile via global_load_lds) -> ds_read current -> MFMA ->
//   __syncthreads()  (one barrier/K-step; its vmcnt(0) drain retires the
//   prefetch which overlapped the whole compute phase).
//   qproj2: A staged as f32 via GLDS (BK=32, 48 KB dbuf), cvt at frag-read.
//   gemm2 (O-proj): bf16, BK=64, 64 KB dbuf.
// attn3 / K,V prep / wt_conv unchanged from round 10.

typedef __attribute__((ext_vector_type(8))) short bf16x8;
typedef __attribute__((ext_vector_type(4))) float f32x4;
typedef __attribute__((ext_vector_type(4))) short short4v;
typedef __attribute__((ext_vector_type(4))) float float4v;
typedef __attribute__((ext_vector_type(2))) unsigned uint2v;
typedef __attribute__((ext_vector_type(4))) unsigned uint4v;

#define DEVINL __device__ __forceinline__

DEVINL short f2bf(float f) {
  unsigned u = __builtin_bit_cast(unsigned, f);
  unsigned r = (u + 0x7FFFu + ((u >> 16) & 1u)) >> 16;  // RNE
  return (short)(unsigned short)r;
}

// packed f32x2 -> bf16x2 (RTNE), single VALU op
DEVINL unsigned pkbf(float lo, float hi) {
  unsigned r;
  asm("v_cvt_pk_bf16_f32 %0, %1, %2" : "=v"(r) : "v"(lo), "v"(hi));
  return r;
}

#define GLDS16(gp, sp)                                                \
  __builtin_amdgcn_global_load_lds(                                   \
      (const __attribute__((address_space(1))) void*)(gp),            \
      (__attribute__((address_space(3))) void*)(sp), 16, 0, 0)

// ---------------- zero fill (float4 granules) ------------------------------
__global__ __launch_bounds__(256) void fill0(float4v* __restrict__ p, int n4) {
  int i = blockIdx.x * 256 + threadIdx.x;
  if (i < n4) p[i] = float4v{0.f, 0.f, 0.f, 0.f};
}

// ---------------- weight transpose+convert: W[K][N] f32 -> Wt[N][K] bf16 ----
__global__ __launch_bounds__(256) void wt_conv(const float* __restrict__ W,
                                               short* __restrict__ Wt,
                                               int K, int N) {
  __shared__ short Tl[64][65];
  const int kt = blockIdx.y * 64, nt = blockIdx.x * 64;
#pragma unroll
  for (int i = 0; i < 16; ++i) {
    int idx = threadIdx.x + i * 256;
    int r = idx >> 6, c = idx & 63;
    Tl[c][r] = f2bf(W[(size_t)(kt + r) * N + nt + c]);
  }
  __syncthreads();
#pragma unroll
  for (int i = 0; i < 16; ++i) {
    int idx = threadIdx.x + i * 256;
    int r = idx >> 6, c = idx & 63;
    Wt[(size_t)(nt + r) * K + kt + c] = Tl[r][c];
  }
}

// ---------------- O-proj: 2-phase dbuf GEMM, bf16 A/B ----------------------
// C[M][512] f32+bias = A[M][512]bf16 @ Bt[512][512]bf16^T. 128x128 tile,
// BK=64, 4 waves, 1-D grid %8==0, XCD swizzle. LDS 64 KB (2 blocks/CU).
__global__ __launch_bounds__(256) void gemm2(const short* __restrict__ A,
                                             const short* __restrict__ Bt,
                                             float* __restrict__ C,
                                             const float* __restrict__ bias) {
  __shared__ short As[2][128 * 64];
  __shared__ short Bs[2][128 * 64];

  const int tid = threadIdx.x;
  const int lane = tid & 63, w = tid >> 6;
  const int wm = w >> 1, wn = w & 1;
  const int quad = lane >> 4, l16 = lane & 15;

  const int cpx = gridDim.x >> 3;
  const int swz = (blockIdx.x & 7) * cpx + (blockIdx.x >> 3);
  const int m0 = (swz >> 2) * 128, n0 = (swz & 3) * 128;

  const int lr = lane >> 3, lc = (lane & 7) * 8;

  f32x4 acc[4][4] = {};

  // prologue: stage tile 0
#pragma unroll
  for (int p = 0; p < 4; ++p) {
    const int rowb = w * 32 + p * 8;
    GLDS16(A + (size_t)(m0 + rowb + lr) * 512 + lc, &As[0][rowb * 64]);
    GLDS16(Bt + (size_t)(n0 + rowb + lr) * 512 + lc, &Bs[0][rowb * 64]);
  }
  __syncthreads();

  for (int t = 0; t < 8; ++t) {
    const int cur = t & 1;
    // stage tile t+1 into the other buffer (overlaps compute below)
    if (t < 7) {
      const int k1 = (t + 1) * 64;
#pragma unroll
      for (int p = 0; p < 4; ++p) {
        const int rowb = w * 32 + p * 8;
        GLDS16(A + (size_t)(m0 + rowb + lr) * 512 + k1 + lc,
               &As[cur ^ 1][rowb * 64]);
        GLDS16(Bt + (size_t)(n0 + rowb + lr) * 512 + k1 + lc,
               &Bs[cur ^ 1][rowb * 64]);
      }
    }
    // compute from current buffer
#pragma unroll
    for (int ks = 0; ks < 2; ++ks) {
      bf16x8 af[4], bfr[4];
#pragma unroll
      for (int m = 0; m < 4; ++m)
        af[m] = *(bf16x8*)&As[cur][(wm * 64 + m * 16 + l16) * 64 + ks * 32 + quad * 8];
#pragma unroll
      for (int n = 0; n < 4; ++n)
        bfr[n] = *(bf16x8*)&Bs[cur][(wn * 64 + n * 16 + l16) * 64 + ks * 32 + quad * 8];
#pragma unroll
      for (int m = 0; m < 4; ++m)
#pragma unroll
        for (int n = 0; n < 4; ++n)
          acc[m][n] = __builtin_amdgcn_mfma_f32_16x16x32_bf16(af[m], bfr[n],
                                                              acc[m][n], 0, 0, 0);
    }
    if (t < 7) __syncthreads();  // drains prefetch (vmcnt0) + guards dbuf
  }

#pragma unroll
  for (int m = 0; m < 4; ++m)
#pragma unroll
    for (int n = 0; n < 4; ++n) {
      const int col = n0 + wn * 64 + n * 16 + l16;
      const int rowb = m0 + wm * 64 + m * 16 + quad * 4;
      const float badd = bias[col];
#pragma unroll
      for (int r = 0; r < 4; ++r)
        C[(size_t)(rowb + r) * 512 + col] = acc[m][n][r] + badd;
    }
}

// ---------------- Q-proj: 2-phase dbuf GEMM, f32 A via GLDS ----------------
// C[M][512] bf16 = A[M][512]f32 @ Bt[512][512]bf16^T. 128x128 tile, BK=32,
// 16 steps, 4 waves. LDS 48 KB (3 blocks/CU). cvt_pk at fragment read.
__global__ __launch_bounds__(256) void qproj2(const float* __restrict__ A,
                                              const short* __restrict__ Bt,
                                              short* __restrict__ C) {
  __shared__ float As[2][128 * 32];  // 2 x 16 KB
  __shared__ short Bs[2][128 * 32];  // 2 x 8 KB

  const int tid = threadIdx.x;
  const int lane = tid & 63, w = tid >> 6;
  const int wm = w >> 1, wn = w & 1;
  const int quad = lane >> 4, l16 = lane & 15;

  const int cpx = gridDim.x >> 3;
  const int swz = (blockIdx.x & 7) * cpx + (blockIdx.x >> 3);
  const int m0 = (swz >> 2) * 128, n0 = (swz & 3) * 128;

  // A staging: 1 KB chunk = 8 rows x 32 f32; lane -> row lane>>3, col (lane&7)*4
  const int alr = lane >> 3, alc = (lane & 7) * 4;
  // B staging: 1 KB chunk = 16 rows x 32 bf16; lane -> row lane>>2, col (lane&3)*8
  const int blr = lane >> 2, blc = (lane & 3) * 8;

  f32x4 acc[4][4] = {};

  // prologue: stage tile 0
#pragma unroll
  for (int p = 0; p < 4; ++p) {
    const int rowb = w * 32 + p * 8;
    GLDS16(A + (size_t)(m0 + rowb + alr) * 512 + alc, &As[0][rowb * 32]);
  }
#pragma unroll
  for (int p = 0; p < 2; ++p) {
    const int rowb = (w * 2 + p) * 16;
    GLDS16(Bt + (size_t)(n0 + rowb + blr) * 512 + blc, &Bs[0][rowb * 32]);
  }
  __syncthreads();

  for (int t = 0; t < 16; ++t) {
    const int cur = t & 1;
    if (t < 15) {
      const int k1 = (t + 1) * 32;
#pragma unroll
      for (int p = 0; p < 4; ++p) {
        const int rowb = w * 32 + p * 8;
        GLDS16(A + (size_t)(m0 + rowb + alr) * 512 + k1 + alc,
               &As[cur ^ 1][rowb * 32]);
      }
#pragma unroll
      for (int p = 0; p < 2; ++p) {
        const int rowb = (w * 2 + p) * 16;
        GLDS16(Bt + (size_t)(n0 + rowb + blr) * 512 + k1 + blc,
               &Bs[cur ^ 1][rowb * 32]);
      }
    }
    // compute: one k-window of 32
    bf16x8 af[4], bfr[4];
#pragma unroll
    for (int m = 0; m < 4; ++m) {
      const float* ap = &As[cur][(wm * 64 + m * 16 + l16) * 32 + quad * 8];
      float4v a0 = *(const float4v*)ap;
      float4v a1 = *(const float4v*)(ap + 4);
      uint4v u = {pkbf(a0[0], a0[1]), pkbf(a0[2], a0[3]),
                  pkbf(a1[0], a1[1]), pkbf(a1[2], a1[3])};
      af[m] = __builtin_bit_cast(bf16x8, u);
    }
#pragma unroll
    for (int n = 0; n < 4; ++n)
      bfr[n] = *(bf16x8*)&Bs[cur][(wn * 64 + n * 16 + l16) * 32 + quad * 8];
#pragma unroll
    for (int m = 0; m < 4; ++m)
#pragma unroll
      for (int n = 0; n < 4; ++n)
        acc[m][n] = __builtin_amdgcn_mfma_f32_16x16x32_bf16(af[m], bfr[n],
                                                            acc[m][n], 0, 0, 0);
    if (t < 15) __syncthreads();
  }

#pragma unroll
  for (int m = 0; m < 4; ++m)
#pragma unroll
    for (int n = 0; n < 4; ++n) {
      const int col = n0 + wn * 64 + n * 16 + l16;
      const int rowb = m0 + wm * 64 + m * 16 + quad * 4;
#pragma unroll
      for (int r = 0; r < 4; ++r)
        C[(size_t)(rowb + r) * 512 + col] = f2bf(acc[m][n][r]);
    }
}

// ---------------- small GEMM (f32 A): C = A[M][K]f32 @ Bt[512][K]^T ---------
// TRANS=0: bf16 C[M][512].  TRANS=1: scatter to Vtg[((b*8+h)*64+d)*104+key].
template <int TRANS>
__global__ __launch_bounds__(256) void gemm_small(const float* __restrict__ A,
                                                  const short* __restrict__ Bt,
                                                  short* __restrict__ C,
                                                  int M, int K) {
  __shared__ short Al[32][40];
  __shared__ short Bl[128][40];

  const int tid = threadIdx.x;
  const int lane = tid & 63, wid = tid >> 6;
  const int wm = wid >> 1, wn = wid & 1;
  const int quad = lane >> 4, l16 = lane & 15;
  const int m0 = blockIdx.y * 32, n0 = blockIdx.x * 128;

  f32x4 acc[4] = {};

  for (int k0 = 0; k0 < K; k0 += 32) {
    for (int idx = tid; idx < 32 * 8; idx += 256) {
      int row = idx >> 3, kq = idx & 7;
      float4v v = {};
      if (m0 + row < M)
        v = *(const float4v*)(A + (size_t)(m0 + row) * K + k0 + kq * 4);
      short4v s = {f2bf(v[0]), f2bf(v[1]), f2bf(v[2]), f2bf(v[3])};
      *(short4v*)&Al[row][kq * 4] = s;
    }
    for (int idx = tid; idx < 512; idx += 256) {
      int row = idx >> 2, kq = idx & 3;
      *(bf16x8*)&Bl[row][kq * 8] =
          *(const bf16x8*)(Bt + (size_t)(n0 + row) * K + k0 + kq * 8);
    }
    __syncthreads();

    bf16x8 a = *(bf16x8*)&Al[wm * 16 + l16][quad * 8];
#pragma unroll
    for (int n = 0; n < 4; ++n) {
      bf16x8 b = *(bf16x8*)&Bl[wn * 64 + n * 16 + l16][quad * 8];
      acc[n] = __builtin_amdgcn_mfma_f32_16x16x32_bf16(a, b, acc[n], 0, 0, 0);
    }
    __syncthreads();
  }

#pragma unroll
  for (int n = 0; n < 4; ++n) {
    const int col = n0 + wn * 64 + n * 16 + l16;
    const int rowb = m0 + wm * 16 + quad * 4;
#pragma unroll
    for (int r = 0; r < 4; ++r) {
      const int rr = rowb + r;
      if (rr < M) {
        if constexpr (TRANS == 0) {
          C[(size_t)rr * 512 + col] = f2bf(acc[n][r]);
        } else {
          const int bb = rr / 77, key = rr - bb * 77;
          C[(size_t)((bb * 8 + (col >> 6)) * 64 + (col & 63)) * 104 + key] =
              f2bf(acc[n][r]);
        }
      }
    }
  }
}

// ---------------- standalone attention -------------------------------------
// 512 thr (8 waves), block = (qtile of 128 rows, head, batch). Each wave owns
// 16 q-rows; Q from global; K [80][72] LDS; V^T [64][104] GLDS; P per-wave
// (no QK->PV barrier). Exactly ONE __syncthreads per block.
__global__ __launch_bounds__(512) void attn3(const short* __restrict__ Qb,
                                             const short* __restrict__ Kb,
                                             const short* __restrict__ Vtg,
                                             short* __restrict__ AOb) {
  __shared__ short Kl[80 * 72];       // 11520 B (rows 77..79 uninit, masked)
  __shared__ short Vt[64 * 104];      // 13312 B
  __shared__ short Pw[8 * 16 * 104];  // 26624 B

  const int tid = threadIdx.x;
  const int lane = tid & 63, w = tid >> 6;
  const int quad = lane >> 4, l16 = lane & 15;
  const int qt = blockIdx.x, h = blockIdx.y, b = blockIdx.z;
  const size_t kbase = ((size_t)b * 77) * 512 + h * 64;

  // stage K rows 0..76 (8 b128 per row)
  for (int idx = tid; idx < 616; idx += 512) {
    const int r = idx >> 3, c = (idx & 7) * 8;
    *(bf16x8*)&Kl[r * 72 + c] =
        *(const bf16x8*)(Kb + kbase + (size_t)r * 512 + c);
  }
  // stage V^T linearly via GLDS (13 chunks of 1 KB)
  for (int cid = w; cid < 13; cid += 8)
    GLDS16(Vtg + (size_t)(b * 8 + h) * 6656 + cid * 512 + lane * 8,
           &Vt[cid * 512]);
  __syncthreads();

  const size_t qrow = (size_t)b * 4096 + qt * 128 + w * 16 + l16;
  const short* qp = Qb + qrow * 512 + h * 64;

  // Q fragment (B operand of sim^T = K . Q^T): col=q=l16, k=d
  bf16x8 qfr[2];
#pragma unroll
  for (int ks = 0; ks < 2; ++ks)
    qfr[ks] = *(const bf16x8*)(qp + ks * 32 + quad * 8);

  // sim^T: 5 frags of 16 keys x 16 q
  f32x4 c[5] = {};
#pragma unroll
  for (int f = 0; f < 5; ++f)
#pragma unroll
    for (int ks = 0; ks < 2; ++ks) {
      bf16x8 a = *(bf16x8*)&Kl[(f * 16 + l16) * 72 + ks * 32 + quad * 8];
      c[f] = __builtin_amdgcn_mfma_f32_16x16x32_bf16(a, qfr[ks], c[f], 0, 0, 0);
    }

  // scale + mask + softmax over keys
  float mx = -1e30f;
#pragma unroll
  for (int f = 0; f < 5; ++f)
#pragma unroll
    for (int r = 0; r < 4; ++r) {
      const int key = f * 16 + quad * 4 + r;
      float v = c[f][r] * 0.125f;
      v = (key < 77) ? v : -1e30f;
      c[f][r] = v;
      mx = fmaxf(mx, v);
    }
  mx = fmaxf(mx, __shfl_xor(mx, 16));
  mx = fmaxf(mx, __shfl_xor(mx, 32));

  short* pbase = Pw + (w * 16 + l16) * 104;
  float sum = 0.f;
#pragma unroll
  for (int f = 0; f < 5; ++f) {
    float e0 = __expf(c[f][0] - mx), e1 = __expf(c[f][1] - mx);
    float e2 = __expf(c[f][2] - mx), e3 = __expf(c[f][3] - mx);
    sum += (e0 + e1) + (e2 + e3);
    uint2v sv2 = {pkbf(e0, e1), pkbf(e2, e3)};
    *(uint2v*)(pbase + f * 16 + quad * 4) = sv2;
  }
  sum += __shfl_xor(sum, 16);
  sum += __shfl_xor(sum, 32);
  const float inv = 1.0f / sum;

  // P fragments: keys 0..63 from LDS; keys 64..79 for quad<2; 80..95 zero.
  bf16x8 pb0 = *(bf16x8*)(pbase + quad * 8);
  bf16x8 pb1 = *(bf16x8*)(pbase + 32 + quad * 8);
  bf16x8 pb2 = bf16x8{0, 0, 0, 0, 0, 0, 0, 0};
  if (quad < 2) pb2 = *(bf16x8*)(pbase + 64 + quad * 8);

  // out^T = V^T . P^T
  f32x4 o[4] = {};
#pragma unroll
  for (int mt = 0; mt < 4; ++mt) {
    const short* vrow = &Vt[(mt * 16 + l16) * 104];
    o[mt] = __builtin_amdgcn_mfma_f32_16x16x32_bf16(
        *(bf16x8*)(vrow + quad * 8), pb0, o[mt], 0, 0, 0);
    o[mt] = __builtin_amdgcn_mfma_f32_16x16x32_bf16(
        *(bf16x8*)(vrow + 32 + quad * 8), pb1, o[mt], 0, 0, 0);
    o[mt] = __builtin_amdgcn_mfma_f32_16x16x32_bf16(
        *(bf16x8*)(vrow + 64 + quad * 8), pb2, o[mt], 0, 0, 0);
  }

  short* op = AOb + qrow * 512 + h * 64;
#pragma unroll
  for (int mt = 0; mt < 4; ++mt) {
    uint2v sv2 = {pkbf(o[mt][0] * inv, o[mt][1] * inv),
                  pkbf(o[mt][2] * inv, o[mt][3] * inv)};
    *(uint2v*)(op + mt * 16 + quad * 4) = sv2;
  }
}

extern "C" void kernel_launch(void* const* d_in, const int* in_sizes, int n_in,
                              void* d_out, int out_size, void* d_ws, size_t ws_size,
                              hipStream_t stream) {
  const float* x   = (const float*)d_in[0];
  const float* ctx = (const float*)d_in[1];
  const float* Wq  = (const float*)d_in[2];
  const float* Wk  = (const float*)d_in[3];
  const float* Wv  = (const float*)d_in[4];
  const float* Wo  = (const float*)d_in[5];
  const float* bo  = (const float*)d_in[6];
  float* out = (float*)d_out;

  char* ws = (char*)d_ws;
  size_t off = 0;
  short* wqt = (short*)(ws + off); off += 512 * 512 * 2;
  short* wkt = (short*)(ws + off); off += 768 * 512 * 2;
  short* wvt = (short*)(ws + off); off += 768 * 512 * 2;
  short* wot = (short*)(ws + off); off += 512 * 512 * 2;
  short* Kb  = (short*)(ws + off); off += 1232 * 512 * 2;
  short* Vtg = (short*)(ws + off); off += (size_t)16 * 8 * 64 * 104 * 2;
  short* Qb  = (short*)(ws + off); off += (size_t)65536 * 512 * 2;
  short* AOb = (short*)(ws + off); off += (size_t)65536 * 512 * 2;

  // weights -> bf16 transposed [N][K]
  wt_conv<<<dim3(8, 8), 256, 0, stream>>>(Wq, wqt, 512, 512);
  wt_conv<<<dim3(8, 12), 256, 0, stream>>>(Wk, wkt, 768, 512);
  wt_conv<<<dim3(8, 12), 256, 0, stream>>>(Wv, wvt, 768, 512);
  wt_conv<<<dim3(8, 8), 256, 0, stream>>>(Wo, wot, 512, 512);

  // zero-fill Vtg pads (16*8*64*104*2 B / 16 = 106496 float4)
  fill0<<<416, 256, 0, stream>>>((float4v*)Vtg, 106496);
  gemm_small<0><<<dim3(4, 39), 256, 0, stream>>>(ctx, wkt, Kb, 1232, 768);
  gemm_small<1><<<dim3(4, 39), 256, 0, stream>>>(ctx, wvt, Vtg, 1232, 768);

  // Q projection (f32 A, 2-phase dbuf) -> Qb bf16
  qproj2<<<2048, 256, 0, stream>>>(x, wqt, Qb);

  // standalone attention -> AOb bf16
  attn3<<<dim3(32, 8, 16), 512, 0, stream>>>(Qb, Kb, Vtg, AOb);

  // output projection + bias (2-phase dbuf) -> f32 d_out
  gemm2<<<2048, 256, 0, stream>>>(AOb, wot, out, bo);
}